// Round 1
// baseline (683.707 us; speedup 1.0000x reference)
//
#include <hip/hip_runtime.h>

#define DN 128
#define DE 64
#define DO 128
#define DIN 320   // 2*DN + DE
#define TN 32     // nodes per finalize block
#define KC 64     // k-chunk
#define LDW (KC + 4)  // padded LDS row stride (floats)

// ---------------------------------------------------------------------------
// Scatter: per edge e, accumulate into dst-node accumulators.
//   agg_src[dst] += node_feats[src]   (128 f32)
//   agg_edge[dst] += edge_feats[e]    (64 f32)
//   deg[dst]     += 1
// 128 threads per edge (f = feature index).
// ---------------------------------------------------------------------------
__global__ __launch_bounds__(256) void scatter_kernel(
    const float* __restrict__ nf, const float* __restrict__ ef,
    const int* __restrict__ src, const int* __restrict__ dst,
    float* __restrict__ agg_src, float* __restrict__ agg_edge,
    float* __restrict__ deg, int E)
{
    long long gid = (long long)blockIdx.x * blockDim.x + threadIdx.x;
    int e = (int)(gid >> 7);
    int f = (int)(gid & 127);
    if (e >= E) return;
    int s = src[e];
    int d = dst[e];
    unsafeAtomicAdd(&agg_src[(long long)d * DN + f], nf[(long long)s * DN + f]);
    if (f < DE) {
        unsafeAtomicAdd(&agg_edge[(long long)d * DE + f], ef[(long long)e * DE + f]);
    }
    if (f == 0) {
        unsafeAtomicAdd(&deg[d], 1.0f);
    }
}

// ---------------------------------------------------------------------------
// Finalize: out[v] = relu( X[v] @ W^T + b ) for deg>0 else relu(node_feats[v])
// X[v] = [agg_src[v]/deg, node_feats[v], agg_edge[v]/deg]  (320 floats)
// Tiled: 32 nodes per block, k-chunks of 64 staged in LDS along with W chunk.
// Thread map: 256 threads = (ty: 16 node-groups of 2) x (tx: 16 out-groups of 8)
//   outputs o = tx + 16*oi  (interleaved -> LDS banks spread, 2-way max)
// ---------------------------------------------------------------------------
__global__ __launch_bounds__(256) void finalize_kernel(
    const float* __restrict__ nf, const float* __restrict__ W,
    const float* __restrict__ b,
    const float* __restrict__ agg_src, const float* __restrict__ agg_edge,
    const float* __restrict__ deg, float* __restrict__ out, int N)
{
    __shared__ float Ws[DO * LDW];     // 128 x 68 floats = 34.8 KB
    __shared__ float Xs[TN * LDW];     // 32 x 68 floats  = 8.7 KB
    __shared__ float degs[TN];
    __shared__ float invd[TN];

    const int tid = threadIdx.x;
    const int tx = tid & 15;
    const int ty = tid >> 4;
    const int node0 = blockIdx.x * TN;

    if (tid < TN) {
        int v = node0 + tid;
        float dg = (v < N) ? deg[v] : 0.0f;
        degs[tid] = dg;
        invd[tid] = (dg > 0.0f) ? (1.0f / dg) : 0.0f;
    }
    __syncthreads();

    float acc[2][8];
#pragma unroll
    for (int ni = 0; ni < 2; ++ni)
#pragma unroll
        for (int oi = 0; oi < 8; ++oi) acc[ni][oi] = 0.0f;

    for (int c = 0; c < DIN / KC; ++c) {
        const int k0 = c * KC;
        // stage W chunk: 128x64 floats, coalesced (consecutive tid -> consecutive k)
        for (int i = tid; i < DO * KC; i += 256) {
            int o = i >> 6;
            int kk = i & 63;
            Ws[o * LDW + kk] = W[o * DIN + k0 + kk];
        }
        // stage X chunk: 32x64 floats
        for (int i = tid; i < TN * KC; i += 256) {
            int n = i >> 6;
            int kk = i & 63;
            int v = node0 + n;
            float x = 0.0f;
            if (v < N) {
                int k = k0 + kk;
                if (k < DN) {
                    x = agg_src[(long long)v * DN + k] * invd[n];
                } else if (k < 2 * DN) {
                    x = nf[(long long)v * DN + (k - DN)];
                } else {
                    x = agg_edge[(long long)v * DE + (k - 2 * DN)] * invd[n];
                }
            }
            Xs[n * LDW + kk] = x;
        }
        __syncthreads();

        const int n0 = ty * 2;
        for (int kk = 0; kk < KC; kk += 4) {
            float4 x0 = *(const float4*)&Xs[(n0 + 0) * LDW + kk];
            float4 x1 = *(const float4*)&Xs[(n0 + 1) * LDW + kk];
#pragma unroll
            for (int oi = 0; oi < 8; ++oi) {
                float4 w = *(const float4*)&Ws[(tx + 16 * oi) * LDW + kk];
                acc[0][oi] += x0.x * w.x + x0.y * w.y + x0.z * w.z + x0.w * w.w;
                acc[1][oi] += x1.x * w.x + x1.y * w.y + x1.z * w.z + x1.w * w.w;
            }
        }
        __syncthreads();
    }

#pragma unroll
    for (int ni = 0; ni < 2; ++ni) {
        int n = ty * 2 + ni;
        int v = node0 + n;
        if (v >= N) continue;
        bool has = degs[n] > 0.0f;
#pragma unroll
        for (int oi = 0; oi < 8; ++oi) {
            int o = tx + 16 * oi;
            float val = has ? (acc[ni][oi] + b[o]) : nf[(long long)v * DN + o];
            out[(long long)v * DO + o] = fmaxf(val, 0.0f);
        }
    }
}

extern "C" void kernel_launch(void* const* d_in, const int* in_sizes, int n_in,
                              void* d_out, int out_size, void* d_ws, size_t ws_size,
                              hipStream_t stream)
{
    const float* nf  = (const float*)d_in[0];
    const float* ef  = (const float*)d_in[1];
    const float* W   = (const float*)d_in[2];
    const float* b   = (const float*)d_in[3];
    const int*   src = (const int*)d_in[4];
    const int*   dst = (const int*)d_in[5];
    float* out = (float*)d_out;

    const int N = in_sizes[0] / DN;
    const int E = in_sizes[4];

    float* agg_src  = (float*)d_ws;
    float* agg_edge = agg_src + (size_t)N * DN;
    float* deg      = agg_edge + (size_t)N * DE;
    const size_t ws_need = ((size_t)N * DN + (size_t)N * DE + (size_t)N) * sizeof(float);
    hipMemsetAsync(d_ws, 0, ws_need, stream);

    const long long total = (long long)E * 128;
    const int blocks = (int)((total + 255) / 256);
    scatter_kernel<<<blocks, 256, 0, stream>>>(nf, ef, src, dst, agg_src, agg_edge, deg, E);

    const int nb = (N + TN - 1) / TN;
    finalize_kernel<<<nb, 256, 0, stream>>>(nf, W, b, agg_src, agg_edge, deg, out, N);
}

// Round 2
// 411.245 us; speedup vs baseline: 1.6625x; 1.6625x over previous
//
#include <hip/hip_runtime.h>

#define DN 128
#define DE 64
#define DO 128
#define DIN 320   // 2*DN + DE
#define TN 64     // nodes per finalize block
#define KC 64     // k-chunk
#define LDW (KC + 4)  // padded LDS row stride (floats)

// ---------------------------------------------------------------------------
// 1) count incoming edges per node
// ---------------------------------------------------------------------------
__global__ __launch_bounds__(256) void count_kernel(
    const int* __restrict__ dst, int* __restrict__ counts, int E)
{
    int e = blockIdx.x * blockDim.x + threadIdx.x;
    if (e < E) atomicAdd(&counts[dst[e]], 1);
}

// ---------------------------------------------------------------------------
// 2) exclusive scan of counts -> row_ptr (single block, 256 threads,
//    each thread owns a contiguous chunk)
// ---------------------------------------------------------------------------
__global__ __launch_bounds__(256) void scan_kernel(
    const int* __restrict__ counts, int* __restrict__ row_ptr, int N, int E)
{
    __shared__ int sdata[256];
    const int tid = threadIdx.x;
    const int chunk = (N + 255) / 256;
    const int start = tid * chunk;
    const int end = min(start + chunk, N);

    int s = 0;
    for (int i = start; i < end; ++i) s += counts[i];
    sdata[tid] = s;
    __syncthreads();
    // Hillis-Steele inclusive scan
    for (int off = 1; off < 256; off <<= 1) {
        int t = (tid >= off) ? sdata[tid - off] : 0;
        __syncthreads();
        sdata[tid] += t;
        __syncthreads();
    }
    int run = sdata[tid] - s;   // exclusive prefix of this thread's chunk
    for (int i = start; i < end; ++i) {
        row_ptr[i] = run;
        run += counts[i];
    }
    if (end == N && start <= N) row_ptr[N] = E;
}

// ---------------------------------------------------------------------------
// 3) fill edge ids per destination (CSR column array)
// ---------------------------------------------------------------------------
__global__ __launch_bounds__(256) void fill_kernel(
    const int* __restrict__ dst, const int* __restrict__ row_ptr,
    int* __restrict__ cursor, int* __restrict__ edge_id, int E)
{
    int e = blockIdx.x * blockDim.x + threadIdx.x;
    if (e >= E) return;
    int d = dst[e];
    int pos = atomicAdd(&cursor[d], 1);
    edge_id[row_ptr[d] + pos] = e;
}

// ---------------------------------------------------------------------------
// 4) gather: one wave per node, no atomics.
//    agg_src[v] = sum nf[src[e]] ; agg_edge[v] = sum ef[e]
//    edge ids + src ids prefetched into lanes, broadcast via shfl.
// ---------------------------------------------------------------------------
__global__ __launch_bounds__(256) void gather_kernel(
    const float* __restrict__ nf, const float* __restrict__ ef,
    const int* __restrict__ src, const int* __restrict__ row_ptr,
    const int* __restrict__ edge_id,
    float* __restrict__ agg_src, float* __restrict__ agg_edge, int N)
{
    const int wave = threadIdx.x >> 6;
    const int lane = threadIdx.x & 63;
    const int v = blockIdx.x * 4 + wave;
    if (v >= N) return;

    const int start = row_ptr[v];
    const int end = row_ptr[v + 1];

    float2 accN = {0.0f, 0.0f};
    float accE = 0.0f;

    for (int base = start; base < end; base += 64) {
        const int cnt = min(64, end - base);
        int e_l = 0, s_l = 0;
        if (lane < cnt) {
            e_l = edge_id[base + lane];
            s_l = src[e_l];
        }
        for (int i = 0; i < cnt; ++i) {
            int e = __shfl(e_l, i, 64);
            int s = __shfl(s_l, i, 64);
            float2 nv = *(const float2*)&nf[(size_t)s * DN + lane * 2];
            accN.x += nv.x;
            accN.y += nv.y;
            accE += ef[(size_t)e * DE + lane];
        }
    }
    *(float2*)&agg_src[(size_t)v * DN + lane * 2] = accN;
    agg_edge[(size_t)v * DE + lane] = accE;
}

// ---------------------------------------------------------------------------
// 5) finalize: out[v] = relu( X[v] @ W^T + b ) for deg>0 else relu(nf[v])
//    X[v] = [agg_src[v]/deg, nf[v], agg_edge[v]/deg]  (320 floats)
//    64 nodes/block; per thread 4 nodes x 8 outs (FMA-bound blocking).
// ---------------------------------------------------------------------------
__global__ __launch_bounds__(256) void finalize_kernel(
    const float* __restrict__ nf, const float* __restrict__ W,
    const float* __restrict__ b,
    const float* __restrict__ agg_src, const float* __restrict__ agg_edge,
    const int* __restrict__ row_ptr, float* __restrict__ out, int N)
{
    __shared__ float Ws[DO * LDW];     // 128 x 68 = 34.8 KB
    __shared__ float Xs[TN * LDW];     // 64 x 68  = 17.4 KB
    __shared__ float invd[TN];
    __shared__ int   degs[TN];

    const int tid = threadIdx.x;
    const int tx = tid & 15;
    const int ty = tid >> 4;
    const int node0 = blockIdx.x * TN;

    if (tid < TN) {
        int v = node0 + tid;
        int dg = 0;
        if (v < N) dg = row_ptr[v + 1] - row_ptr[v];
        degs[tid] = dg;
        invd[tid] = (dg > 0) ? (1.0f / (float)dg) : 0.0f;
    }
    __syncthreads();

    float acc[4][8];
#pragma unroll
    for (int ni = 0; ni < 4; ++ni)
#pragma unroll
        for (int oi = 0; oi < 8; ++oi) acc[ni][oi] = 0.0f;

    for (int c = 0; c < DIN / KC; ++c) {
        const int k0 = c * KC;
        // stage W chunk: 128x64 floats, coalesced
        for (int i = tid; i < DO * KC; i += 256) {
            int o = i >> 6;
            int kk = i & 63;
            Ws[o * LDW + kk] = W[o * DIN + k0 + kk];
        }
        // stage X chunk: 64x64 floats
        for (int i = tid; i < TN * KC; i += 256) {
            int n = i >> 6;
            int kk = i & 63;
            int v = node0 + n;
            float x = 0.0f;
            if (v < N) {
                int k = k0 + kk;
                if (k < DN) {
                    x = agg_src[(size_t)v * DN + k] * invd[n];
                } else if (k < 2 * DN) {
                    x = nf[(size_t)v * DN + (k - DN)];
                } else {
                    x = agg_edge[(size_t)v * DE + (k - 2 * DN)] * invd[n];
                }
            }
            Xs[n * LDW + kk] = x;
        }
        __syncthreads();

        const int n0 = ty * 4;
        for (int kk = 0; kk < KC; kk += 4) {
            float4 xr[4];
#pragma unroll
            for (int ni = 0; ni < 4; ++ni)
                xr[ni] = *(const float4*)&Xs[(n0 + ni) * LDW + kk];
#pragma unroll
            for (int oi = 0; oi < 8; ++oi) {
                float4 w = *(const float4*)&Ws[(tx + 16 * oi) * LDW + kk];
#pragma unroll
                for (int ni = 0; ni < 4; ++ni) {
                    acc[ni][oi] += xr[ni].x * w.x + xr[ni].y * w.y +
                                   xr[ni].z * w.z + xr[ni].w * w.w;
                }
            }
        }
        __syncthreads();
    }

#pragma unroll
    for (int ni = 0; ni < 4; ++ni) {
        int n = ty * 4 + ni;
        int v = node0 + n;
        if (v >= N) continue;
        bool has = degs[n] > 0;
#pragma unroll
        for (int oi = 0; oi < 8; ++oi) {
            int o = tx + 16 * oi;
            float val = has ? (acc[ni][oi] + b[o]) : nf[(size_t)v * DN + o];
            out[(size_t)v * DO + o] = fmaxf(val, 0.0f);
        }
    }
}

extern "C" void kernel_launch(void* const* d_in, const int* in_sizes, int n_in,
                              void* d_out, int out_size, void* d_ws, size_t ws_size,
                              hipStream_t stream)
{
    const float* nf  = (const float*)d_in[0];
    const float* ef  = (const float*)d_in[1];
    const float* W   = (const float*)d_in[2];
    const float* b   = (const float*)d_in[3];
    const int*   src = (const int*)d_in[4];
    const int*   dst = (const int*)d_in[5];
    float* out = (float*)d_out;

    const int N = in_sizes[0] / DN;
    const int E = in_sizes[4];

    // workspace layout
    char* ws = (char*)d_ws;
    int* counts   = (int*)ws;                       ws += (size_t)N * sizeof(int);
    int* cursor   = (int*)ws;                       ws += (size_t)N * sizeof(int);
    int* row_ptr  = (int*)ws;                       ws += (size_t)(N + 1) * sizeof(int);
    int* edge_id  = (int*)ws;                       ws += (size_t)E * sizeof(int);
    float* agg_src  = (float*)ws;                   ws += (size_t)N * DN * sizeof(float);
    float* agg_edge = (float*)ws;

    // zero counts + cursor (contiguous)
    hipMemsetAsync(counts, 0, (size_t)2 * N * sizeof(int), stream);

    const int eb = (E + 255) / 256;
    count_kernel<<<eb, 256, 0, stream>>>(dst, counts, E);
    scan_kernel<<<1, 256, 0, stream>>>(counts, row_ptr, N, E);
    fill_kernel<<<eb, 256, 0, stream>>>(dst, row_ptr, cursor, edge_id, E);

    const int gb = (N + 3) / 4;
    gather_kernel<<<gb, 256, 0, stream>>>(nf, ef, src, row_ptr, edge_id,
                                          agg_src, agg_edge, N);

    const int nb = (N + TN - 1) / TN;
    finalize_kernel<<<nb, 256, 0, stream>>>(nf, W, b, agg_src, agg_edge,
                                            row_ptr, out, N);
}

// Round 3
// 307.458 us; speedup vs baseline: 2.2237x; 1.3376x over previous
//
#include <hip/hip_runtime.h>

#define DN 128
#define DE 64
#define DO 128
#define DIN 320       // 2*DN + DE
#define LDX 72        // padded LDS row stride in bf16 elems (144 B)

typedef short bf16x8 __attribute__((ext_vector_type(8)));
typedef float f32x4 __attribute__((ext_vector_type(4)));
typedef unsigned short ushort_t;
typedef unsigned long long u64;

__device__ inline unsigned short f2bf(float f) {
    unsigned u = __builtin_bit_cast(unsigned, f);
    u = (u + 0x7fffu + ((u >> 16) & 1u)) >> 16;   // round-to-nearest-even
    return (unsigned short)u;
}
__device__ inline unsigned pk2(float a, float b) {
    return (unsigned)f2bf(a) | ((unsigned)f2bf(b) << 16);
}

// ---------------------------------------------------------------------------
// 0) convert W (f32 [128x320]) -> bf16 once
// ---------------------------------------------------------------------------
__global__ __launch_bounds__(256) void convert_w_kernel(
    const float* __restrict__ W, unsigned short* __restrict__ Wbf, int n4)
{
    int i = blockIdx.x * 256 + threadIdx.x;
    if (i >= n4) return;
    const float4 v = *(const float4*)&W[i * 4];
    u64 val = (u64)pk2(v.x, v.y) | ((u64)pk2(v.z, v.w) << 32);
    *(u64*)&Wbf[i * 4] = val;
}

// ---------------------------------------------------------------------------
// 1) count incoming edges per node
// ---------------------------------------------------------------------------
__global__ __launch_bounds__(256) void count_kernel(
    const int* __restrict__ dst, int* __restrict__ counts, int E)
{
    int e = blockIdx.x * blockDim.x + threadIdx.x;
    if (e < E) atomicAdd(&counts[dst[e]], 1);
}

// ---------------------------------------------------------------------------
// 2) exclusive scan of counts -> row_ptr (single block, 1024 threads)
// ---------------------------------------------------------------------------
__global__ __launch_bounds__(1024) void scan_kernel(
    const int* __restrict__ counts, int* __restrict__ row_ptr, int N, int E)
{
    __shared__ int sdata[1024];
    const int tid = threadIdx.x;
    const int chunk = (N + 1023) / 1024;
    const int start = tid * chunk;
    const int end = min(start + chunk, N);

    int s = 0;
    for (int i = start; i < end; ++i) s += counts[i];
    sdata[tid] = s;
    __syncthreads();
    for (int off = 1; off < 1024; off <<= 1) {
        int t = (tid >= off) ? sdata[tid - off] : 0;
        __syncthreads();
        sdata[tid] += t;
        __syncthreads();
    }
    int run = sdata[tid] - s;
    for (int i = start; i < end; ++i) {
        row_ptr[i] = run;
        run += counts[i];
    }
    if (end == N && start <= N) row_ptr[N] = E;
}

// ---------------------------------------------------------------------------
// 3) fill edge ids per destination (CSR column array)
// ---------------------------------------------------------------------------
__global__ __launch_bounds__(256) void fill_kernel(
    const int* __restrict__ dst, const int* __restrict__ row_ptr,
    int* __restrict__ cursor, int* __restrict__ edge_id, int E)
{
    int e = blockIdx.x * blockDim.x + threadIdx.x;
    if (e >= E) return;
    int d = dst[e];
    int pos = atomicAdd(&cursor[d], 1);
    edge_id[row_ptr[d] + pos] = e;
}

// ---------------------------------------------------------------------------
// 4) gather: one wave per node, no atomics; writes MEAN (already /deg) as bf16
//    unroll-2 -> 2x memory-level parallelism on the nf L2 gathers
// ---------------------------------------------------------------------------
__global__ __launch_bounds__(256) void gather_kernel(
    const float* __restrict__ nf, const float* __restrict__ ef,
    const int* __restrict__ src, const int* __restrict__ row_ptr,
    const int* __restrict__ edge_id,
    unsigned short* __restrict__ agg_src_bf,
    unsigned short* __restrict__ agg_edge_bf, int N)
{
    const int wave = threadIdx.x >> 6;
    const int lane = threadIdx.x & 63;
    const int v = blockIdx.x * 4 + wave;
    if (v >= N) return;

    const int start = row_ptr[v];
    const int end = row_ptr[v + 1];
    const int deg = end - start;

    float ax0 = 0.f, ay0 = 0.f, ax1 = 0.f, ay1 = 0.f;
    float ae0 = 0.f, ae1 = 0.f;

    for (int base = start; base < end; base += 64) {
        const int cnt = min(64, end - base);
        int e_l = 0, s_l = 0;
        if (lane < cnt) {
            e_l = edge_id[base + lane];
            s_l = src[e_l];
        }
        int i = 0;
        for (; i + 1 < cnt; i += 2) {
            int e0 = __shfl(e_l, i, 64);
            int s0 = __shfl(s_l, i, 64);
            int e1 = __shfl(e_l, i + 1, 64);
            int s1 = __shfl(s_l, i + 1, 64);
            float2 n0 = *(const float2*)&nf[(size_t)s0 * DN + lane * 2];
            float2 n1 = *(const float2*)&nf[(size_t)s1 * DN + lane * 2];
            float f0 = ef[(size_t)e0 * DE + lane];
            float f1 = ef[(size_t)e1 * DE + lane];
            ax0 += n0.x; ay0 += n0.y;
            ax1 += n1.x; ay1 += n1.y;
            ae0 += f0;   ae1 += f1;
        }
        if (i < cnt) {
            int e0 = __shfl(e_l, i, 64);
            int s0 = __shfl(s_l, i, 64);
            float2 n0 = *(const float2*)&nf[(size_t)s0 * DN + lane * 2];
            ax0 += n0.x; ay0 += n0.y;
            ae0 += ef[(size_t)e0 * DE + lane];
        }
    }
    const float inv = (deg > 0) ? (1.0f / (float)deg) : 0.0f;
    const float mx = (ax0 + ax1) * inv;
    const float my = (ay0 + ay1) * inv;
    const float me = (ae0 + ae1) * inv;
    *(unsigned*)&agg_src_bf[(size_t)v * DN + lane * 2] = pk2(mx, my);
    agg_edge_bf[(size_t)v * DE + lane] = f2bf(me);
}

// ---------------------------------------------------------------------------
// 5) finalize (MFMA): out[v] = relu( X[v] @ W^T + b ) ; deg==0 -> relu(nf[v])
//    X[v] = [mean_src(bf16), nf(f32->bf16), mean_edge(bf16)]  (320)
//    64 nodes x 128 outs per block; 4 waves; 16x16x32 bf16 MFMA.
// ---------------------------------------------------------------------------
__global__ __launch_bounds__(256) void finalize_kernel(
    const float* __restrict__ nf, const unsigned short* __restrict__ Wbf,
    const float* __restrict__ b,
    const unsigned short* __restrict__ agg_src_bf,
    const unsigned short* __restrict__ agg_edge_bf,
    const int* __restrict__ row_ptr, float* __restrict__ out, int N)
{
    __shared__ unsigned short Ws[DO * LDX];   // 18.4 KB
    __shared__ unsigned short Xs[64 * LDX];   //  9.2 KB
    __shared__ float bs[DO];
    __shared__ int degs[64];

    const int tid = threadIdx.x;
    const int lane = tid & 63;
    const int w = tid >> 6;
    const int node0 = blockIdx.x * 64;

    if (tid < DO) bs[tid] = b[tid];
    if (tid < 64) {
        int v = node0 + tid;
        degs[tid] = (v < N) ? (row_ptr[v + 1] - row_ptr[v]) : 0;
    }

    f32x4 acc[8];
#pragma unroll
    for (int r = 0; r < 8; ++r) acc[r] = (f32x4){0.f, 0.f, 0.f, 0.f};

    for (int c = 0; c < 5; ++c) {
        const int k0 = c * 64;
        __syncthreads();
        // stage W chunk: 128 x 64 bf16, 8B per thread per iter
#pragma unroll
        for (int it = 0; it < 8; ++it) {
            int i4 = tid + it * 256;
            int o = i4 >> 4;
            int kk = (i4 & 15) * 4;
            *(u64*)&Ws[o * LDX + kk] = *(const u64*)&Wbf[o * DIN + k0 + kk];
        }
        // stage X chunk: 64 x 64 bf16
        if (c < 2) {
#pragma unroll
            for (int it = 0; it < 4; ++it) {
                int i4 = tid + it * 256;
                int n = i4 >> 4;
                int kk = (i4 & 15) * 4;
                int v = node0 + n;
                u64 val = 0;
                if (v < N) val = *(const u64*)&agg_src_bf[(size_t)v * DN + k0 + kk];
                *(u64*)&Xs[n * LDX + kk] = val;
            }
        } else if (c < 4) {
#pragma unroll
            for (int it = 0; it < 4; ++it) {
                int i4 = tid + it * 256;
                int n = i4 >> 4;
                int kk = (i4 & 15) * 4;
                int v = node0 + n;
                u64 val = 0;
                if (v < N) {
                    const float4 x = *(const float4*)&nf[(size_t)v * DN + (c - 2) * 64 + kk];
                    val = (u64)pk2(x.x, x.y) | ((u64)pk2(x.z, x.w) << 32);
                }
                *(u64*)&Xs[n * LDX + kk] = val;
            }
        } else {
#pragma unroll
            for (int it = 0; it < 4; ++it) {
                int i4 = tid + it * 256;
                int n = i4 >> 4;
                int kk = (i4 & 15) * 4;
                int v = node0 + n;
                u64 val = 0;
                if (v < N) val = *(const u64*)&agg_edge_bf[(size_t)v * DE + kk];
                *(u64*)&Xs[n * LDX + kk] = val;
            }
        }
        __syncthreads();

        const int xrow = 16 * w + (lane & 15);
        const int kgrp = (lane >> 4) * 8;
#pragma unroll
        for (int t = 0; t < 2; ++t) {
            bf16x8 a = *(const bf16x8*)&Xs[xrow * LDX + t * 32 + kgrp];
#pragma unroll
            for (int r = 0; r < 8; ++r) {
                bf16x8 bw = *(const bf16x8*)&Ws[(16 * r + (lane & 15)) * LDX + t * 32 + kgrp];
                acc[r] = __builtin_amdgcn_mfma_f32_16x16x32_bf16(a, bw, acc[r], 0, 0, 0);
            }
        }
    }

    // epilogue: C layout col=lane&15, row=(lane>>4)*4+reg
    const int col = lane & 15;
#pragma unroll
    for (int r = 0; r < 8; ++r) {
        const int o = 16 * r + col;
        const float bo = bs[o];
#pragma unroll
        for (int reg = 0; reg < 4; ++reg) {
            const int n = 16 * w + (lane >> 4) * 4 + reg;
            const int v = node0 + n;
            if (v >= N) continue;
            float val = (degs[n] > 0) ? (acc[r][reg] + bo)
                                      : nf[(size_t)v * DN + o];
            out[(size_t)v * DO + o] = fmaxf(val, 0.0f);
        }
    }
}

extern "C" void kernel_launch(void* const* d_in, const int* in_sizes, int n_in,
                              void* d_out, int out_size, void* d_ws, size_t ws_size,
                              hipStream_t stream)
{
    const float* nf  = (const float*)d_in[0];
    const float* ef  = (const float*)d_in[1];
    const float* W   = (const float*)d_in[2];
    const float* b   = (const float*)d_in[3];
    const int*   src = (const int*)d_in[4];
    const int*   dst = (const int*)d_in[5];
    float* out = (float*)d_out;

    const int N = in_sizes[0] / DN;
    const int E = in_sizes[4];

    char* p = (char*)d_ws;
    int* counts  = (int*)p;  p += (size_t)N * 4;
    int* cursor  = (int*)p;  p += (size_t)N * 4;
    int* row_ptr = (int*)p;  p += (size_t)(N + 1) * 4;
    int* edge_id = (int*)p;  p += (size_t)E * 4;
    p = (char*)(((uintptr_t)p + 15) & ~(uintptr_t)15);
    unsigned short* agg_src_bf  = (unsigned short*)p;  p += (size_t)N * DN * 2;
    unsigned short* agg_edge_bf = (unsigned short*)p;  p += (size_t)N * DE * 2;
    unsigned short* Wbf         = (unsigned short*)p;

    hipMemsetAsync(counts, 0, (size_t)2 * N * sizeof(int), stream);

    convert_w_kernel<<<(DO * DIN / 4 + 255) / 256, 256, 0, stream>>>(W, Wbf, DO * DIN / 4);

    const int eb = (E + 255) / 256;
    count_kernel<<<eb, 256, 0, stream>>>(dst, counts, E);
    scan_kernel<<<1, 1024, 0, stream>>>(counts, row_ptr, N, E);
    fill_kernel<<<eb, 256, 0, stream>>>(dst, row_ptr, cursor, edge_id, E);

    const int gb = (N + 3) / 4;
    gather_kernel<<<gb, 256, 0, stream>>>(nf, ef, src, row_ptr, edge_id,
                                          agg_src_bf, agg_edge_bf, N);

    const int nb = (N + 63) / 64;
    finalize_kernel<<<nb, 256, 0, stream>>>(nf, Wbf, b, agg_src_bf, agg_edge_bf,
                                            row_ptr, out, N);
}

// Round 4
// 288.016 us; speedup vs baseline: 2.3738x; 1.0675x over previous
//
#include <hip/hip_runtime.h>

#define DN 128
#define DE 64
#define DO 128
#define DIN 320       // 2*DN + DE
#define LDX 72        // padded LDS row stride in bf16 elems (144 B)

typedef short bf16x8 __attribute__((ext_vector_type(8)));
typedef float f32x4 __attribute__((ext_vector_type(4)));
typedef unsigned long long u64;

__device__ inline unsigned short f2bf(float f) {
    unsigned u = __builtin_bit_cast(unsigned, f);
    u = (u + 0x7fffu + ((u >> 16) & 1u)) >> 16;   // round-to-nearest-even
    return (unsigned short)u;
}
__device__ inline unsigned pk2(float a, float b) {
    return (unsigned)f2bf(a) | ((unsigned)f2bf(b) << 16);
}

// ---------------------------------------------------------------------------
// 0) convert W (f32 [128x320]) -> bf16 once
// ---------------------------------------------------------------------------
__global__ __launch_bounds__(256) void convert_w_kernel(
    const float* __restrict__ W, unsigned short* __restrict__ Wbf, int n4)
{
    int i = blockIdx.x * 256 + threadIdx.x;
    if (i >= n4) return;
    const float4 v = *(const float4*)&W[i * 4];
    u64 val = (u64)pk2(v.x, v.y) | ((u64)pk2(v.z, v.w) << 32);
    *(u64*)&Wbf[i * 4] = val;
}

// ---------------------------------------------------------------------------
// 1) count incoming edges per node
// ---------------------------------------------------------------------------
__global__ __launch_bounds__(256) void count_kernel(
    const int* __restrict__ dst, int* __restrict__ counts, int E)
{
    int e = blockIdx.x * blockDim.x + threadIdx.x;
    if (e < E) atomicAdd(&counts[dst[e]], 1);
}

// ---------------------------------------------------------------------------
// 2) exclusive scan of counts -> row_ptr (single block, 1024 threads)
// ---------------------------------------------------------------------------
__global__ __launch_bounds__(1024) void scan_kernel(
    const int* __restrict__ counts, int* __restrict__ row_ptr, int N, int E)
{
    __shared__ int sdata[1024];
    const int tid = threadIdx.x;
    const int chunk = (N + 1023) / 1024;
    const int start = tid * chunk;
    const int end = min(start + chunk, N);

    int s = 0;
    for (int i = start; i < end; ++i) s += counts[i];
    sdata[tid] = s;
    __syncthreads();
    for (int off = 1; off < 1024; off <<= 1) {
        int t = (tid >= off) ? sdata[tid - off] : 0;
        __syncthreads();
        sdata[tid] += t;
        __syncthreads();
    }
    int run = sdata[tid] - s;
    for (int i = start; i < end; ++i) {
        row_ptr[i] = run;
        run += counts[i];
    }
    if (end == N && start <= N) row_ptr[N] = E;
}

// ---------------------------------------------------------------------------
// 3) fill (e, src[e]) pairs per destination (CSR column array).
//    src[e] read is COALESCED here -> gather never does a random 4B pull.
// ---------------------------------------------------------------------------
__global__ __launch_bounds__(256) void fill_kernel(
    const int* __restrict__ dst, const int* __restrict__ src,
    const int* __restrict__ row_ptr,
    int* __restrict__ cursor, int2* __restrict__ es, int E)
{
    int e = blockIdx.x * blockDim.x + threadIdx.x;
    if (e >= E) return;
    int d = dst[e];
    int s = src[e];
    int pos = atomicAdd(&cursor[d], 1);
    es[row_ptr[d] + pos] = make_int2(e, s);
}

// ---------------------------------------------------------------------------
// 4) gather: one wave per node, no atomics; writes MEAN (already /deg) as bf16
//    float4 wide loads: one wave-load = 4 ef rows (lane>>4 = edge) or
//    2 nf rows (lane>>5 = edge). 8 edges unrolled -> 6 loads in flight.
//    ef is a one-pass 205MB stream -> nontemporal (keep nf in L2/L3).
// ---------------------------------------------------------------------------
__global__ __launch_bounds__(256) void gather_kernel(
    const float* __restrict__ nf, const float* __restrict__ ef,
    const int2* __restrict__ es, const int* __restrict__ row_ptr,
    unsigned short* __restrict__ agg_src_bf,
    unsigned short* __restrict__ agg_edge_bf, int N)
{
    const int wave = threadIdx.x >> 6;
    const int lane = threadIdx.x & 63;
    const int v = blockIdx.x * 4 + wave;
    if (v >= N) return;

    const int start = row_ptr[v];
    const int end = row_ptr[v + 1];
    const int deg = end - start;

    const int qN = lane & 31;        // nf feature quad
    const int hN = lane >> 5;        // nf edge-half
    const int qE = lane & 15;        // ef feature quad
    const int gE = lane >> 4;        // ef edge-group

    f32x4 accN = {0.f, 0.f, 0.f, 0.f};
    f32x4 accE = {0.f, 0.f, 0.f, 0.f};

    for (int base = start; base < end; base += 64) {
        const int cnt = min(64, end - base);
        int e_l = 0, s_l = 0;
        if (lane < cnt) {
            int2 p = es[base + lane];
            e_l = p.x;
            s_l = p.y;
        }
        for (int i = 0; i < cnt; i += 8) {
            // broadcast edge/src ids for this 8-edge group
            int e0 = __shfl(e_l, i + gE, 64);
            int e1 = __shfl(e_l, i + 4 + gE, 64);
            int sA = __shfl(s_l, i + hN, 64);
            int sB = __shfl(s_l, i + 2 + hN, 64);
            int sC = __shfl(s_l, i + 4 + hN, 64);
            int sD = __shfl(s_l, i + 6 + hN, 64);
            // issue all 6 wave-loads (addresses valid even for tail: id=0)
            f32x4 fe0 = __builtin_nontemporal_load((const f32x4*)&ef[(size_t)e0 * DE + qE * 4]);
            f32x4 fe1 = __builtin_nontemporal_load((const f32x4*)&ef[(size_t)e1 * DE + qE * 4]);
            f32x4 fA = *(const f32x4*)&nf[(size_t)sA * DN + qN * 4];
            f32x4 fB = *(const f32x4*)&nf[(size_t)sB * DN + qN * 4];
            f32x4 fC = *(const f32x4*)&nf[(size_t)sC * DN + qN * 4];
            f32x4 fD = *(const f32x4*)&nf[(size_t)sD * DN + qN * 4];
            // predicated accumulate (tail edges contribute 0)
            if (i + gE < cnt)     accE += fe0;
            if (i + 4 + gE < cnt) accE += fe1;
            if (i + hN < cnt)     accN += fA;
            if (i + 2 + hN < cnt) accN += fB;
            if (i + 4 + hN < cnt) accN += fC;
            if (i + 6 + hN < cnt) accN += fD;
        }
    }

    // cross-group reductions
    accN.x += __shfl_xor(accN.x, 32, 64);
    accN.y += __shfl_xor(accN.y, 32, 64);
    accN.z += __shfl_xor(accN.z, 32, 64);
    accN.w += __shfl_xor(accN.w, 32, 64);
    accE.x += __shfl_xor(accE.x, 16, 64);
    accE.y += __shfl_xor(accE.y, 16, 64);
    accE.z += __shfl_xor(accE.z, 16, 64);
    accE.w += __shfl_xor(accE.w, 16, 64);
    accE.x += __shfl_xor(accE.x, 32, 64);
    accE.y += __shfl_xor(accE.y, 32, 64);
    accE.z += __shfl_xor(accE.z, 32, 64);
    accE.w += __shfl_xor(accE.w, 32, 64);

    const float inv = (deg > 0) ? (1.0f / (float)deg) : 0.0f;
    if (lane < 32) {
        u64 val = (u64)pk2(accN.x * inv, accN.y * inv) |
                  ((u64)pk2(accN.z * inv, accN.w * inv) << 32);
        *(u64*)&agg_src_bf[(size_t)v * DN + qN * 4] = val;
    } else if (lane < 48) {
        u64 val = (u64)pk2(accE.x * inv, accE.y * inv) |
                  ((u64)pk2(accE.z * inv, accE.w * inv) << 32);
        *(u64*)&agg_edge_bf[(size_t)v * DE + qE * 4] = val;
    }
}

// ---------------------------------------------------------------------------
// 5) finalize (MFMA): out[v] = relu( X[v] @ W^T + b ) ; deg==0 -> relu(nf[v])
//    X[v] = [mean_src(bf16), nf(f32->bf16), mean_edge(bf16)]  (320)
//    64 nodes x 128 outs per block; 4 waves; 16x16x32 bf16 MFMA.
// ---------------------------------------------------------------------------
__global__ __launch_bounds__(256) void finalize_kernel(
    const float* __restrict__ nf, const unsigned short* __restrict__ Wbf,
    const float* __restrict__ b,
    const unsigned short* __restrict__ agg_src_bf,
    const unsigned short* __restrict__ agg_edge_bf,
    const int* __restrict__ row_ptr, float* __restrict__ out, int N)
{
    __shared__ unsigned short Ws[DO * LDX];   // 18.4 KB
    __shared__ unsigned short Xs[64 * LDX];   //  9.2 KB
    __shared__ float bs[DO];
    __shared__ int degs[64];

    const int tid = threadIdx.x;
    const int lane = tid & 63;
    const int w = tid >> 6;
    const int node0 = blockIdx.x * 64;

    if (tid < DO) bs[tid] = b[tid];
    if (tid < 64) {
        int v = node0 + tid;
        degs[tid] = (v < N) ? (row_ptr[v + 1] - row_ptr[v]) : 0;
    }

    f32x4 acc[8];
#pragma unroll
    for (int r = 0; r < 8; ++r) acc[r] = (f32x4){0.f, 0.f, 0.f, 0.f};

    for (int c = 0; c < 5; ++c) {
        const int k0 = c * 64;
        __syncthreads();
#pragma unroll
        for (int it = 0; it < 8; ++it) {
            int i4 = tid + it * 256;
            int o = i4 >> 4;
            int kk = (i4 & 15) * 4;
            *(u64*)&Ws[o * LDX + kk] = *(const u64*)&Wbf[o * DIN + k0 + kk];
        }
        if (c < 2) {
#pragma unroll
            for (int it = 0; it < 4; ++it) {
                int i4 = tid + it * 256;
                int n = i4 >> 4;
                int kk = (i4 & 15) * 4;
                int v = node0 + n;
                u64 val = 0;
                if (v < N) val = *(const u64*)&agg_src_bf[(size_t)v * DN + k0 + kk];
                *(u64*)&Xs[n * LDX + kk] = val;
            }
        } else if (c < 4) {
#pragma unroll
            for (int it = 0; it < 4; ++it) {
                int i4 = tid + it * 256;
                int n = i4 >> 4;
                int kk = (i4 & 15) * 4;
                int v = node0 + n;
                u64 val = 0;
                if (v < N) {
                    const float4 x = *(const float4*)&nf[(size_t)v * DN + (c - 2) * 64 + kk];
                    val = (u64)pk2(x.x, x.y) | ((u64)pk2(x.z, x.w) << 32);
                }
                *(u64*)&Xs[n * LDX + kk] = val;
            }
        } else {
#pragma unroll
            for (int it = 0; it < 4; ++it) {
                int i4 = tid + it * 256;
                int n = i4 >> 4;
                int kk = (i4 & 15) * 4;
                int v = node0 + n;
                u64 val = 0;
                if (v < N) val = *(const u64*)&agg_edge_bf[(size_t)v * DE + kk];
                *(u64*)&Xs[n * LDX + kk] = val;
            }
        }
        __syncthreads();

        const int xrow = 16 * w + (lane & 15);
        const int kgrp = (lane >> 4) * 8;
#pragma unroll
        for (int t = 0; t < 2; ++t) {
            bf16x8 a = *(const bf16x8*)&Xs[xrow * LDX + t * 32 + kgrp];
#pragma unroll
            for (int r = 0; r < 8; ++r) {
                bf16x8 bw = *(const bf16x8*)&Ws[(16 * r + (lane & 15)) * LDX + t * 32 + kgrp];
                acc[r] = __builtin_amdgcn_mfma_f32_16x16x32_bf16(a, bw, acc[r], 0, 0, 0);
            }
        }
    }

    // epilogue: C layout col=lane&15, row=(lane>>4)*4+reg
    const int col = lane & 15;
#pragma unroll
    for (int r = 0; r < 8; ++r) {
        const int o = 16 * r + col;
        const float bo = bs[o];
#pragma unroll
        for (int reg = 0; reg < 4; ++reg) {
            const int n = 16 * w + (lane >> 4) * 4 + reg;
            const int v = node0 + n;
            if (v >= N) continue;
            float val = (degs[n] > 0) ? (acc[r][reg] + bo)
                                      : nf[(size_t)v * DN + o];
            out[(size_t)v * DO + o] = fmaxf(val, 0.0f);
        }
    }
}

extern "C" void kernel_launch(void* const* d_in, const int* in_sizes, int n_in,
                              void* d_out, int out_size, void* d_ws, size_t ws_size,
                              hipStream_t stream)
{
    const float* nf  = (const float*)d_in[0];
    const float* ef  = (const float*)d_in[1];
    const float* W   = (const float*)d_in[2];
    const float* b   = (const float*)d_in[3];
    const int*   src = (const int*)d_in[4];
    const int*   dst = (const int*)d_in[5];
    float* out = (float*)d_out;

    const int N = in_sizes[0] / DN;
    const int E = in_sizes[4];

    char* p = (char*)d_ws;
    int* counts  = (int*)p;  p += (size_t)N * 4;
    int* cursor  = (int*)p;  p += (size_t)N * 4;
    int* row_ptr = (int*)p;  p += (size_t)(N + 1) * 4;
    p = (char*)(((uintptr_t)p + 15) & ~(uintptr_t)15);
    int2* es     = (int2*)p; p += (size_t)E * 8;
    unsigned short* agg_src_bf  = (unsigned short*)p;  p += (size_t)N * DN * 2;
    unsigned short* agg_edge_bf = (unsigned short*)p;  p += (size_t)N * DE * 2;
    unsigned short* Wbf         = (unsigned short*)p;

    hipMemsetAsync(counts, 0, (size_t)2 * N * sizeof(int), stream);

    convert_w_kernel<<<(DO * DIN / 4 + 255) / 256, 256, 0, stream>>>(W, Wbf, DO * DIN / 4);

    const int eb = (E + 255) / 256;
    count_kernel<<<eb, 256, 0, stream>>>(dst, counts, E);
    scan_kernel<<<1, 1024, 0, stream>>>(counts, row_ptr, N, E);
    fill_kernel<<<eb, 256, 0, stream>>>(dst, src, row_ptr, cursor, es, E);

    const int gb = (N + 3) / 4;
    gather_kernel<<<gb, 256, 0, stream>>>(nf, ef, es, row_ptr,
                                          agg_src_bf, agg_edge_bf, N);

    const int nb = (N + 63) / 64;
    finalize_kernel<<<nb, 256, 0, stream>>>(nf, Wbf, b, agg_src_bf, agg_edge_bf,
                                            row_ptr, out, N);
}

// Round 5
// 265.772 us; speedup vs baseline: 2.5725x; 1.0837x over previous
//
#include <hip/hip_runtime.h>

#define DN 128
#define DE 64
#define DO 128
#define DIN 320       // 2*DN + DE
#define LDX 72        // padded LDS row stride in bf16 elems (144 B)

typedef short bf16x8 __attribute__((ext_vector_type(8)));
typedef float f32x4 __attribute__((ext_vector_type(4)));
typedef unsigned long long u64;

__device__ inline unsigned short f2bf(float f) {
    unsigned u = __builtin_bit_cast(unsigned, f);
    u = (u + 0x7fffu + ((u >> 16) & 1u)) >> 16;   // round-to-nearest-even
    return (unsigned short)u;
}
__device__ inline unsigned pk2(float a, float b) {
    return (unsigned)f2bf(a) | ((unsigned)f2bf(b) << 16);
}
__device__ inline float bf2f(unsigned short h) {
    unsigned u = ((unsigned)h) << 16;
    return __builtin_bit_cast(float, u);
}

// ---------------------------------------------------------------------------
// 0) convert W [128x320] and nf [N x 128] f32 -> bf16 (one pass, 4 f32/thread)
// ---------------------------------------------------------------------------
__global__ __launch_bounds__(256) void convert_kernel(
    const float* __restrict__ W, const float* __restrict__ nf,
    unsigned short* __restrict__ Wbf, unsigned short* __restrict__ nfbf,
    int nW4, int n4tot)
{
    int i = blockIdx.x * 256 + threadIdx.x;
    if (i >= n4tot) return;
    const float* sp;
    unsigned short* dp;
    int j;
    if (i < nW4) { sp = W;  dp = Wbf;  j = i; }
    else         { sp = nf; dp = nfbf; j = i - nW4; }
    const float4 v = *(const float4*)&sp[(size_t)j * 4];
    u64 val = (u64)pk2(v.x, v.y) | ((u64)pk2(v.z, v.w) << 32);
    *(u64*)&dp[(size_t)j * 4] = val;
}

// ---------------------------------------------------------------------------
// 1) count incoming edges per node
// ---------------------------------------------------------------------------
__global__ __launch_bounds__(256) void count_kernel(
    const int* __restrict__ dst, int* __restrict__ counts, int E)
{
    int e = blockIdx.x * blockDim.x + threadIdx.x;
    if (e < E) atomicAdd(&counts[dst[e]], 1);
}

// ---------------------------------------------------------------------------
// 2) exclusive scan of counts -> row_ptr (single block, 1024 threads)
// ---------------------------------------------------------------------------
__global__ __launch_bounds__(1024) void scan_kernel(
    const int* __restrict__ counts, int* __restrict__ row_ptr, int N, int E)
{
    __shared__ int sdata[1024];
    const int tid = threadIdx.x;
    const int chunk = (N + 1023) / 1024;
    const int start = tid * chunk;
    const int end = min(start + chunk, N);

    int s = 0;
    for (int i = start; i < end; ++i) s += counts[i];
    sdata[tid] = s;
    __syncthreads();
    for (int off = 1; off < 1024; off <<= 1) {
        int t = (tid >= off) ? sdata[tid - off] : 0;
        __syncthreads();
        sdata[tid] += t;
        __syncthreads();
    }
    int run = sdata[tid] - s;
    for (int i = start; i < end; ++i) {
        row_ptr[i] = run;
        run += counts[i];
    }
    if (end == N && start <= N) row_ptr[N] = E;
}

// ---------------------------------------------------------------------------
// 3) fill (e, src[e]) pairs per destination (CSR column array).
//    src[e] read is COALESCED here -> gather never does a random 4B pull.
// ---------------------------------------------------------------------------
__global__ __launch_bounds__(256) void fill_kernel(
    const int* __restrict__ dst, const int* __restrict__ src,
    const int* __restrict__ row_ptr,
    int* __restrict__ cursor, int2* __restrict__ es, int E)
{
    int e = blockIdx.x * blockDim.x + threadIdx.x;
    if (e >= E) return;
    int d = dst[e];
    int s = src[e];
    int pos = atomicAdd(&cursor[d], 1);
    es[row_ptr[d] + pos] = make_int2(e, s);
}

// ---------------------------------------------------------------------------
// 4) gather: one wave per node, no atomics; writes MEAN (already /deg) as bf16
//    nf is pre-converted bf16: one 16B/lane wave-load = 4 nf rows (256B each)
//    or 4 ef f32 rows. 16 edges unrolled -> 8 wave-loads in flight.
//    ef is a one-pass 205MB stream -> nontemporal.
// ---------------------------------------------------------------------------
__global__ __launch_bounds__(256) void gather_kernel(
    const unsigned short* __restrict__ nfbf, const float* __restrict__ ef,
    const int2* __restrict__ es, const int* __restrict__ row_ptr,
    unsigned short* __restrict__ agg_src_bf,
    unsigned short* __restrict__ agg_edge_bf, int N)
{
    const int wave = threadIdx.x >> 6;
    const int lane = threadIdx.x & 63;
    const int v = blockIdx.x * 4 + wave;
    if (v >= N) return;

    const int start = row_ptr[v];
    const int end = row_ptr[v + 1];
    const int deg = end - start;

    const int g = lane >> 4;     // edge subgroup 0..3
    const int q = lane & 15;     // feature segment within row

    float accN[8];
#pragma unroll
    for (int j = 0; j < 8; ++j) accN[j] = 0.f;
    f32x4 accE = {0.f, 0.f, 0.f, 0.f};

    for (int base = start; base < end; base += 64) {
        const int cnt = min(64, end - base);
        int e_l = 0, s_l = 0;
        if (lane < cnt) {
            int2 p = es[base + lane];
            e_l = p.x;
            s_l = p.y;
        }
        for (int i = 0; i < cnt; i += 16) {
            const int s0 = __shfl(s_l, i + g, 64);
            const int s1 = __shfl(s_l, i + 4 + g, 64);
            const int s2 = __shfl(s_l, i + 8 + g, 64);
            const int s3 = __shfl(s_l, i + 12 + g, 64);
            const int e0 = __shfl(e_l, i + g, 64);
            const int e1 = __shfl(e_l, i + 4 + g, 64);
            const int e2 = __shfl(e_l, i + 8 + g, 64);
            const int e3 = __shfl(e_l, i + 12 + g, 64);
            // issue all 8 wave-loads (addresses valid even for tail: id=0)
            bf16x8 n0 = *(const bf16x8*)&nfbf[(size_t)s0 * DN + q * 8];
            bf16x8 n1 = *(const bf16x8*)&nfbf[(size_t)s1 * DN + q * 8];
            bf16x8 n2 = *(const bf16x8*)&nfbf[(size_t)s2 * DN + q * 8];
            bf16x8 n3 = *(const bf16x8*)&nfbf[(size_t)s3 * DN + q * 8];
            f32x4 f0 = __builtin_nontemporal_load((const f32x4*)&ef[(size_t)e0 * DE + q * 4]);
            f32x4 f1 = __builtin_nontemporal_load((const f32x4*)&ef[(size_t)e1 * DE + q * 4]);
            f32x4 f2 = __builtin_nontemporal_load((const f32x4*)&ef[(size_t)e2 * DE + q * 4]);
            f32x4 f3 = __builtin_nontemporal_load((const f32x4*)&ef[(size_t)e3 * DE + q * 4]);
            // predicated accumulate (tail edges contribute 0)
            if (i + g < cnt) {
#pragma unroll
                for (int j = 0; j < 8; ++j) accN[j] += bf2f((unsigned short)n0[j]);
                accE += f0;
            }
            if (i + 4 + g < cnt) {
#pragma unroll
                for (int j = 0; j < 8; ++j) accN[j] += bf2f((unsigned short)n1[j]);
                accE += f1;
            }
            if (i + 8 + g < cnt) {
#pragma unroll
                for (int j = 0; j < 8; ++j) accN[j] += bf2f((unsigned short)n2[j]);
                accE += f2;
            }
            if (i + 12 + g < cnt) {
#pragma unroll
                for (int j = 0; j < 8; ++j) accN[j] += bf2f((unsigned short)n3[j]);
                accE += f3;
            }
        }
    }

    // reduce across the 4 edge subgroups (lanes differing in bits 4,5)
#pragma unroll
    for (int j = 0; j < 8; ++j) {
        accN[j] += __shfl_xor(accN[j], 16, 64);
        accN[j] += __shfl_xor(accN[j], 32, 64);
    }
#pragma unroll
    for (int j = 0; j < 4; ++j) {
        accE[j] += __shfl_xor(accE[j], 16, 64);
        accE[j] += __shfl_xor(accE[j], 32, 64);
    }

    const float inv = (deg > 0) ? (1.0f / (float)deg) : 0.0f;
    if (g == 0) {
        uint4 val;
        val.x = pk2(accN[0] * inv, accN[1] * inv);
        val.y = pk2(accN[2] * inv, accN[3] * inv);
        val.z = pk2(accN[4] * inv, accN[5] * inv);
        val.w = pk2(accN[6] * inv, accN[7] * inv);
        *(uint4*)&agg_src_bf[(size_t)v * DN + q * 8] = val;
    } else if (g == 1) {
        u64 val = (u64)pk2(accE[0] * inv, accE[1] * inv) |
                  ((u64)pk2(accE[2] * inv, accE[3] * inv) << 32);
        *(u64*)&agg_edge_bf[(size_t)v * DE + q * 4] = val;
    }
}

// ---------------------------------------------------------------------------
// 5) finalize (MFMA): out[v] = relu( X[v] @ W^T + b ) ; deg==0 -> relu(nf[v])
//    X[v] = [mean_src(bf16), nfbf(bf16), mean_edge(bf16)]  (320)
//    64 nodes x 128 outs per block; 4 waves; 16x16x32 bf16 MFMA.
// ---------------------------------------------------------------------------
__global__ __launch_bounds__(256) void finalize_kernel(
    const float* __restrict__ nf, const unsigned short* __restrict__ nfbf,
    const unsigned short* __restrict__ Wbf, const float* __restrict__ b,
    const unsigned short* __restrict__ agg_src_bf,
    const unsigned short* __restrict__ agg_edge_bf,
    const int* __restrict__ row_ptr, float* __restrict__ out, int N)
{
    __shared__ unsigned short Ws[DO * LDX];   // 18.4 KB
    __shared__ unsigned short Xs[64 * LDX];   //  9.2 KB
    __shared__ float bs[DO];
    __shared__ int degs[64];

    const int tid = threadIdx.x;
    const int lane = tid & 63;
    const int w = tid >> 6;
    const int node0 = blockIdx.x * 64;

    if (tid < DO) bs[tid] = b[tid];
    if (tid < 64) {
        int v = node0 + tid;
        degs[tid] = (v < N) ? (row_ptr[v + 1] - row_ptr[v]) : 0;
    }

    f32x4 acc[8];
#pragma unroll
    for (int r = 0; r < 8; ++r) acc[r] = (f32x4){0.f, 0.f, 0.f, 0.f};

    for (int c = 0; c < 5; ++c) {
        const int k0 = c * 64;
        __syncthreads();
#pragma unroll
        for (int it = 0; it < 8; ++it) {
            int i4 = tid + it * 256;
            int o = i4 >> 4;
            int kk = (i4 & 15) * 4;
            *(u64*)&Ws[o * LDX + kk] = *(const u64*)&Wbf[o * DIN + k0 + kk];
        }
#pragma unroll
        for (int it = 0; it < 4; ++it) {
            int i4 = tid + it * 256;
            int n = i4 >> 4;
            int kk = (i4 & 15) * 4;
            int v = node0 + n;
            u64 val = 0;
            if (v < N) {
                if (c < 2) {
                    val = *(const u64*)&agg_src_bf[(size_t)v * DN + k0 + kk];
                } else if (c < 4) {
                    val = *(const u64*)&nfbf[(size_t)v * DN + (c - 2) * 64 + kk];
                } else {
                    val = *(const u64*)&agg_edge_bf[(size_t)v * DE + kk];
                }
            }
            *(u64*)&Xs[n * LDX + kk] = val;
        }
        __syncthreads();

        const int xrow = 16 * w + (lane & 15);
        const int kgrp = (lane >> 4) * 8;
#pragma unroll
        for (int t = 0; t < 2; ++t) {
            bf16x8 a = *(const bf16x8*)&Xs[xrow * LDX + t * 32 + kgrp];
#pragma unroll
            for (int r = 0; r < 8; ++r) {
                bf16x8 bw = *(const bf16x8*)&Ws[(16 * r + (lane & 15)) * LDX + t * 32 + kgrp];
                acc[r] = __builtin_amdgcn_mfma_f32_16x16x32_bf16(a, bw, acc[r], 0, 0, 0);
            }
        }
    }

    // epilogue: C layout col=lane&15, row=(lane>>4)*4+reg
    const int col = lane & 15;
#pragma unroll
    for (int r = 0; r < 8; ++r) {
        const int o = 16 * r + col;
        const float bo = bs[o];
#pragma unroll
        for (int reg = 0; reg < 4; ++reg) {
            const int n = 16 * w + (lane >> 4) * 4 + reg;
            const int v = node0 + n;
            if (v >= N) continue;
            float val = (degs[n] > 0) ? (acc[r][reg] + bo)
                                      : nf[(size_t)v * DN + o];
            out[(size_t)v * DO + o] = fmaxf(val, 0.0f);
        }
    }
}

extern "C" void kernel_launch(void* const* d_in, const int* in_sizes, int n_in,
                              void* d_out, int out_size, void* d_ws, size_t ws_size,
                              hipStream_t stream)
{
    const float* nf  = (const float*)d_in[0];
    const float* ef  = (const float*)d_in[1];
    const float* W   = (const float*)d_in[2];
    const float* b   = (const float*)d_in[3];
    const int*   src = (const int*)d_in[4];
    const int*   dst = (const int*)d_in[5];
    float* out = (float*)d_out;

    const int N = in_sizes[0] / DN;
    const int E = in_sizes[4];

    char* p = (char*)d_ws;
    int* counts  = (int*)p;  p += (size_t)N * 4;
    int* cursor  = (int*)p;  p += (size_t)N * 4;
    int* row_ptr = (int*)p;  p += (size_t)(N + 1) * 4;
    p = (char*)(((uintptr_t)p + 15) & ~(uintptr_t)15);
    int2* es     = (int2*)p; p += (size_t)E * 8;
    unsigned short* agg_src_bf  = (unsigned short*)p;  p += (size_t)N * DN * 2;
    unsigned short* agg_edge_bf = (unsigned short*)p;  p += (size_t)N * DE * 2;
    unsigned short* nfbf        = (unsigned short*)p;  p += (size_t)N * DN * 2;
    unsigned short* Wbf         = (unsigned short*)p;

    hipMemsetAsync(counts, 0, (size_t)2 * N * sizeof(int), stream);

    const int nW4 = DO * DIN / 4;
    const int n4tot = nW4 + N * DN / 4;
    convert_kernel<<<(n4tot + 255) / 256, 256, 0, stream>>>(W, nf, Wbf, nfbf, nW4, n4tot);

    const int eb = (E + 255) / 256;
    count_kernel<<<eb, 256, 0, stream>>>(dst, counts, E);
    scan_kernel<<<1, 1024, 0, stream>>>(counts, row_ptr, N, E);
    fill_kernel<<<eb, 256, 0, stream>>>(dst, src, row_ptr, cursor, es, E);

    const int gb = (N + 3) / 4;
    gather_kernel<<<gb, 256, 0, stream>>>(nfbf, ef, es, row_ptr,
                                          agg_src_bf, agg_edge_bf, N);

    const int nb = (N + 63) / 64;
    finalize_kernel<<<nb, 256, 0, stream>>>(nf, nfbf, Wbf, b, agg_src_bf,
                                            agg_edge_bf, row_ptr, out, N);
}